// Round 1
// 420.112 us; speedup vs baseline: 1.0661x; 1.0661x over previous
//
#include <hip/hip_runtime.h>
#include <math.h>

#define BB 8
#define NN 9216
#define FF 1024
#define KK 4096
#define VOX 0.2f

typedef float f32x4 __attribute__((ext_vector_type(4)));

// Workspace layout (ints):
//   cnt       : BB*KK      (zeroed by hipMemsetAsync; doubles as hist + position counter)
//   keys      : BB*NN      (packed: (key<<14) | pos_within_voxel)
//   start     : BB*KK
//   rank_info : BB*KK*2    (int2 {start, count} per compacted voxel rank)
//   counts    : BB
//   order     : BB*NN

__global__ __launch_bounds__(256) void k_hist(const float* __restrict__ xyz,
                                              int* __restrict__ keys,
                                              int* __restrict__ cnt) {
    int p = blockIdx.x * 256 + threadIdx.x;
    if (p >= BB * NN) return;
    int b = p / NN;
    const float* x = xyz + (size_t)p * 3;
    // Per-axis min subtraction in the reference shifts every key by a constant
    // per axis: grouping and lexicographic order are invariant, so skip it.
    // Keep x/VOX (not x*5.0f) to match reference rounding exactly.
    int c0 = (int)floorf(x[0] / VOX);
    int c1 = (int)floorf(x[1] / VOX);
    int c2 = (int)floorf(x[2] / VOX);
    c0 = min(max(c0, 0), 15);
    c1 = min(max(c1, 0), 15);
    c2 = min(max(c2, 0), 15);
    int key = (c0 << 8) | (c1 << 4) | c2;
    // The histogram atomic already yields this point's position within its
    // voxel -- pack it so k_order needs no second atomic pass / cursor array.
    int pos = atomicAdd(&cnt[b * KK + key], 1);   // pos < N=9216 < 2^14
    keys[p] = (key << 14) | pos;
}

__global__ __launch_bounds__(1024) void k_scan(const int* __restrict__ cnt,
                                               int* __restrict__ start,
                                               int2* __restrict__ rank_info,
                                               int* __restrict__ counts) {
    const int b = blockIdx.x;
    const int t = threadIdx.x;
    const int lane = t & 63;
    const int wv = t >> 6;                 // 16 waves of 64
    __shared__ unsigned long long s_wave[16];

    int4 c4 = ((const int4*)(cnt + b * KK))[t];   // base = t*4, 16B aligned
    int c[4] = {c4.x, c4.y, c4.z, c4.w};
    int to = 0, tc = 0;
    #pragma unroll
    for (int j = 0; j < 4; j++) { to += (c[j] > 0); tc += c[j]; }
    unsigned long long v = ((unsigned long long)(unsigned)to << 32) | (unsigned)tc;

    // intra-wave inclusive scan: 6 shuffle steps, no barriers
    unsigned long long x = v;
    #pragma unroll
    for (int off = 1; off < 64; off <<= 1) {
        unsigned long long y = __shfl_up(x, off, 64);
        if (lane >= off) x += y;
    }
    if (lane == 63) s_wave[wv] = x;
    __syncthreads();
    // wave 0 scans the 16 wave totals (inclusive)
    if (wv == 0) {
        unsigned long long w = (lane < 16) ? s_wave[lane] : 0ULL;
        #pragma unroll
        for (int off = 1; off < 16; off <<= 1) {
            unsigned long long y = __shfl_up(w, off, 64);
            if (lane >= off) w += y;
        }
        if (lane < 16) s_wave[lane] = w;
    }
    __syncthreads();

    unsigned long long incl = x + (wv ? s_wave[wv - 1] : 0ULL);
    unsigned long long excl = incl - v;
    int rank = (int)(excl >> 32);
    int st   = (int)(excl & 0xffffffffULL);
    int4 s4;
    int sts[4];
    #pragma unroll
    for (int j = 0; j < 4; j++) {
        sts[j] = st;
        if (c[j] > 0) {
            rank_info[(size_t)b * KK + rank] = make_int2(st, c[j]);
            rank++;
        }
        st += c[j];
    }
    s4.x = sts[0]; s4.y = sts[1]; s4.z = sts[2]; s4.w = sts[3];
    ((int4*)(start + b * KK))[t] = s4;
    if (t == 1023) counts[b] = (int)(incl >> 32);
}

__global__ __launch_bounds__(256) void k_order(const int* __restrict__ keys,
                                               const int* __restrict__ start,
                                               int* __restrict__ order,
                                               const int* __restrict__ counts,
                                               float* __restrict__ out_off) {
    int p = blockIdx.x * 256 + threadIdx.x;
    if (p == 0) {  // counts[] is complete (k_scan precedes in stream order)
        int cum = 0;
        for (int b = 0; b < BB; b++) {
            cum += counts[b];
            out_off[b] = (float)cum;
        }
    }
    if (p >= BB * NN) return;
    int b = p / NN;
    int lp = p - b * NN;
    int packed = keys[p];
    int key = packed >> 14;
    int pos = packed & 0x3fff;
    // pure scatter -- no atomics; pos came from the hist atomic
    order[(size_t)b * NN + start[b * KK + key] + pos] = lp;
}

__global__ __launch_bounds__(256) void k_pool(const float* __restrict__ feat,
                                              const int2* __restrict__ rank_info,
                                              const int* __restrict__ order,
                                              const int* __restrict__ counts,
                                              float* __restrict__ out) {
    const int blk = blockIdx.x;          // b*KK + k
    const int b = blk >> 12;
    const int k = blk & (KK - 1);
    const int t = threadIdx.x;           // 256 threads * float4 = 1024 floats
    f32x4 a0 = {0.f, 0.f, 0.f, 0.f};
    f32x4 a1 = {0.f, 0.f, 0.f, 0.f};
    if (k < counts[b]) {
        int2 info = rank_info[(size_t)b * KK + k];
        const int s = info.x, c = info.y;
        const float* fb = feat + (size_t)b * NN * FF;
        const int* ob = order + (size_t)b * NN + s;
        int i = 0;
        for (; i + 1 < c; i += 2) {
            int p0 = ob[i], p1 = ob[i + 1];
            // streamed once -- keep out of L2
            f32x4 v0 = __builtin_nontemporal_load((const f32x4*)(fb + (size_t)p0 * FF) + t);
            f32x4 v1 = __builtin_nontemporal_load((const f32x4*)(fb + (size_t)p1 * FF) + t);
            a0 += v0; a1 += v1;
        }
        if (i < c) {
            int p0 = ob[i];
            a0 += __builtin_nontemporal_load((const f32x4*)(fb + (size_t)p0 * FF) + t);
        }
        a0 = (a0 + a1) / (float)c;
    }
    __builtin_nontemporal_store(a0, (f32x4*)(out + (size_t)blk * FF) + t);
}

extern "C" void kernel_launch(void* const* d_in, const int* in_sizes, int n_in,
                              void* d_out, int out_size, void* d_ws, size_t ws_size,
                              hipStream_t stream) {
    const float* features = (const float*)d_in[0];   // (B, N, F) f32
    const float* xyz      = (const float*)d_in[1];   // (B, N, 3) f32
    float* out = (float*)d_out;                      // B*K*F pooled + B offsets (f32)

    int* ws        = (int*)d_ws;
    int* cnt       = ws;                             // B*K
    int* keys      = cnt    + BB * KK;               // B*N
    int* start     = keys   + BB * NN;               // B*K
    int2* rankinfo = (int2*)(start + BB * KK);       // B*K int2
    int* counts    = (int*)(rankinfo + BB * KK);     // B
    int* order     = counts + BB;                    // B*N

    hipMemsetAsync(cnt, 0, BB * KK * sizeof(int), stream);
    k_hist<<<(BB * NN + 255) / 256, 256, 0, stream>>>(xyz, keys, cnt);
    k_scan<<<BB, 1024, 0, stream>>>(cnt, start, rankinfo, counts);
    k_order<<<(BB * NN + 255) / 256, 256, 0, stream>>>(keys, start, order, counts,
                                                       out + (size_t)BB * KK * FF);
    k_pool<<<BB * KK, 256, 0, stream>>>(features, rankinfo, order, counts, out);
}